// Round 8
// baseline (739.790 us; speedup 1.0000x reference)
//
#include <hip/hip_runtime.h>
#include <hip/hip_bf16.h>

#define NPTS 600000
#define NKEYS (1 << 22)          // 2 * 128^3 compact key space
#define CHUNK 4096
#define NPART (NKEYS / CHUNK)    // 1024

typedef unsigned int u32;
typedef unsigned short u16;
typedef __attribute__((ext_vector_type(8))) short short8;   // 8 bf16 = 4 VGPRs
typedef __attribute__((ext_vector_type(4))) float f32x4;

__device__ __forceinline__ u16 f2bf(float x) {
  union { float f; u32 u; } c; c.f = x;
  u32 r = c.u + 0x7fffu + ((c.u >> 16) & 1u);   // RNE, inputs finite
  return (u16)(r >> 16);
}

// ---- K0a: fold BN into alpha/beta -------------------------------------------
__global__ void k0a_bn(const float* __restrict__ s, const float* __restrict__ b,
                       const float* __restrict__ m, const float* __restrict__ v,
                       float* __restrict__ ab) {
  int c = threadIdx.x;   // 64 threads
  float a = s[c] * rsqrtf(v[c] + 1e-5f);
  ab[c] = a;
  ab[64 + c] = b[c] - m[c] * a;
}

// ---- K0b: W[27][cin][cout] f32 -> Wt[27][cout][cin] bf16 --------------------
__global__ void k0b_wt(const float* __restrict__ W, u16* __restrict__ Wt) {
  int e = blockIdx.x * 256 + threadIdx.x;
  if (e >= 27 * 4096) return;
  int k = e >> 12, rem = e & 4095, cin = rem >> 6, cout = rem & 63;
  Wt[(k << 12) + (cout << 6) + cin] = f2bf(W[e]);
}

// ---- K1: compact keys + per-voxel point counts ------------------------------
__global__ void k1_keys(const int* __restrict__ coords, int* __restrict__ keys,
                        u32* __restrict__ lut) {
  int i = blockIdx.x * 256 + threadIdx.x;
  if (i >= NPTS) return;
  int4 c4 = *(const int4*)(coords + i * 4);
  int k = (c4.w << 21) | ((c4.x >> 1) << 14) | ((c4.y >> 1) << 7) | (c4.z >> 1);
  keys[i] = k;
  atomicAdd(&lut[k], 1u);   // count points per voxel (~600k atomics total)
}

// ---- K2a: per-chunk occupied-voxel counts -----------------------------------
__global__ void k2a_part(const u32* __restrict__ lut, u32* __restrict__ partials) {
  __shared__ u32 sd[256];
  int blk = blockIdx.x, t = threadIdx.x;
  const u32* p = lut + blk * CHUNK;
  u32 s = 0;
  for (int j = t; j < CHUNK; j += 256) s += (p[j] != 0u);
  sd[t] = s; __syncthreads();
  for (int o = 128; o > 0; o >>= 1) { if (t < o) sd[t] += sd[t + o]; __syncthreads(); }
  if (t == 0) partials[blk] = sd[0];
}

// ---- K2b: scan the 1024 partials (exclusive) + total U ----------------------
__global__ void k2b_top(u32* __restrict__ partials) {
  __shared__ u32 sh[NPART];
  int t = threadIdx.x;   // 1024 threads
  u32 x = partials[t];
  sh[t] = x; __syncthreads();
  for (int off = 1; off < NPART; off <<= 1) {
    u32 add = (t >= off) ? sh[t - off] : 0u;
    __syncthreads();
    sh[t] += add;
    __syncthreads();
  }
  partials[t] = sh[t] - x;                       // exclusive
  if (t == NPART - 1) partials[NPART] = sh[t];   // total unique count U
}

// ---- K2c: fill lut ((rank+1)|multi<<31 or 0), r2k, zero multi f32 rows ------
__global__ void k2c_fill(u32* __restrict__ lut, const u32* __restrict__ partials,
                         int* __restrict__ r2k, float* __restrict__ fds32) {
  __shared__ u32 tsum[256];
  int blk = blockIdx.x, t = threadIdx.x;
  int base = blk * CHUNK + t * 16;
  u32 loc[16]; u32 s = 0;
#pragma unroll
  for (int j = 0; j < 16; j++) { loc[j] = lut[base + j]; s += (loc[j] != 0u); }
  tsum[t] = s; __syncthreads();
  for (int off = 1; off < 256; off <<= 1) {
    u32 add = (t >= off) ? tsum[t - off] : 0u;
    __syncthreads();
    tsum[t] += add;
    __syncthreads();
  }
  u32 rank = partials[blk] + tsum[t] - s;   // exclusive rank for first elem
#pragma unroll
  for (int j = 0; j < 16; j++) {
    if (loc[j]) {
      u32 flag = (loc[j] > 1u) ? 0x80000000u : 0u;
      lut[base + j] = (rank + 1u) | flag;
      r2k[rank] = base + j;
      if (flag) {   // zero the f32 accumulation row for multi-point voxels
        float4 z = {0.f, 0.f, 0.f, 0.f};
        float* d = fds32 + ((size_t)rank << 6);
#pragma unroll
        for (int c = 0; c < 16; c++) *(float4*)(d + c * 4) = z;
      }
      rank++;
    } else lut[base + j] = 0u;
  }
}

// ---- K3: fused segment-sum: singles -> bf16 direct, multis -> f32 atomics ---
__global__ void k3_seg(const float* __restrict__ feats, const int* __restrict__ keys,
                       const u32* __restrict__ lut, float* __restrict__ fds32,
                       u16* __restrict__ fdsb) {
  int idx = blockIdx.x * 256 + threadIdx.x;   // NPTS*16 threads, 4 ch each
  if (idx >= NPTS * 16) return;
  int i = idx >> 4, q = (idx & 15) << 2;
  u32 lv = lut[keys[i]];
  u32 r = (lv & 0x7fffffffu) - 1u;
  float4 v = *(const float4*)(feats + (size_t)i * 64 + q);
  if (lv >> 31) {               // ~13% of points: shared voxel, accumulate f32
    float* dst = fds32 + ((size_t)r << 6) + q;
    atomicAdd(dst + 0, v.x); atomicAdd(dst + 1, v.y);
    atomicAdd(dst + 2, v.z); atomicAdd(dst + 3, v.w);
  } else {                      // ~87%: sole occupant, convert + plain store
    ushort4 o;
    o.x = f2bf(v.x); o.y = f2bf(v.y); o.z = f2bf(v.z); o.w = f2bf(v.w);
    *(ushort4*)(fdsb + ((size_t)r << 6) + q) = o;
  }
}

// ---- K3b: convert only multi-voxel rows f32 -> bf16 -------------------------
__global__ void k3b_fix(const int* __restrict__ r2k, const u32* __restrict__ lut,
                        const u32* __restrict__ pU,
                        const float* __restrict__ fds32, u16* __restrict__ fdsb) {
  int idx = blockIdx.x * 256 + threadIdx.x;   // NPTS*4 threads, 16 ch each
  int r = idx >> 2;
  if (r >= (int)(*pU)) return;
  u32 lv = lut[r2k[r]];
  if (!(lv >> 31)) return;
  int q = (idx & 3) << 4;
  const float* src = fds32 + ((size_t)r << 6) + q;
  u16* dst = fdsb + ((size_t)r << 6) + q;
#pragma unroll
  for (int j = 0; j < 4; j++) {
    float4 v = *(const float4*)(src + j * 4);
    ushort4 o;
    o.x = f2bf(v.x); o.y = f2bf(v.y); o.z = f2bf(v.z); o.w = f2bf(v.w);
    *(ushort4*)(dst + j * 4) = o;
  }
}

// ---- K4: producer/consumer gather-GEMM + BN/ReLU (global_load_lds) ----------
// Block = 320 thr (5 waves), 64 output rows. Wave 0 = producer: per offset k,
// lane l gathers row (rbase+l)'s neighbor via 8x global_load_lds (16B each,
// direct HBM/L2 -> LDS, NO VGPR round trip). LDS layout [chunk j][row]:
// instruction j writes lane l's 16B to slot + j*1024 + l*16 (linear in lane
// order = the gload_lds hardware pattern; rule #21 both-sides-same-formula).
// Consumers (waves 1-4) = 2x2 quadrants: wave owns 32 rows x 32 couts ->
// A-LDS-read dup and B-L1-read dup both 2x (vs 4x in the 1D splits).
// One barrier per offset; ring slot k&1 read, (k+1)&1 written (disjoint).
__global__ __launch_bounds__(320, 6) void k4_conv(
    const u32* __restrict__ lut, const int* __restrict__ r2k,
    const u16* __restrict__ fdsb, const u16* __restrict__ Wt,
    const u32* __restrict__ pU, const float* __restrict__ ab,
    float* __restrict__ out) {
  __shared__ __align__(16) char ldsA[2][8192];   // ring: [chunk 0..7][row 0..63] x 16B
  const u32 U = *pU;
  int tid = threadIdx.x;
  int w = tid >> 6, l = tid & 63;
  // XCD-bijective swizzle (grid multiple of 8): rank-contiguous chunks per XCD.
  int bid = blockIdx.x;
  int cpx = (int)gridDim.x >> 3;
  int swz = (bid & 7) * cpx + (bid >> 3);
  int rbase = swz * 64;

  // ---- producer state (wave 0): lane l owns output row rbase + l ----
  int key = -1, x = 0, y = 0, z = 0;
  if (w == 0) {
    int r = rbase + l;
    key = ((u32)r < U) ? r2k[r] : -1;
    z = key & 127; y = (key >> 7) & 127; x = (key >> 14) & 127;
  }
  // branchless lut probe for offset k (sentinel entry NKEYS == 0 for OOB)
  auto probe = [&](int k) -> u32 {
    int dx = k / 9 - 1, dy = (k / 3) % 3 - 1, dz = k % 3 - 1;
    int nx = x + dx, ny = y + dy, nz = z + dz;
    bool ok = (key >= 0) & ((u32)nx < 128u) & ((u32)ny < 128u) & ((u32)nz < 128u);
    int a = ok ? (key + dx * 16384 + dy * 128 + dz) : NKEYS;
    return lut[a];
  };
  // direct global->LDS gather of the 128B fdsb row (8 x 16B, no VGPR trip)
  auto gather = [&](int slot, u32 lvv) {
    u32 row = lvv ? ((lvv & 0x7fffffffu) - 1u) : (u32)NPTS;   // zero row
    const char* fr = (const char*)(fdsb + ((size_t)row << 6));
    char* slab = &ldsA[slot][0];
#define GL(J) __builtin_amdgcn_global_load_lds( \
      (const __attribute__((address_space(1))) void*)(fr + (J) * 16), \
      (__attribute__((address_space(3))) void*)(slab + (J) * 1024), 16, 0, 0);
    GL(0) GL(1) GL(2) GL(3) GL(4) GL(5) GL(6) GL(7)
#undef GL
  };

  // ---- consumer state (waves 1-4): quadrant wi (rows), wj (couts) ----
  int wi = (w - 1) >> 1, wj = (w - 1) & 1;
  int col = l & 15, kg = l >> 4;
  f32x4 acc[2][2] = {};   // [rt][ct]

  // prologue: fill slot 0, prime the probe pipeline
  u32 lv_cur = 0;
  if (w == 0) {
    gather(0, probe(0));
    lv_cur = probe(1);
  }
  __syncthreads();   // compiler emits vmcnt(0) before barrier -> slot 0 ready

  for (int k = 0; k < 27; k++) {
    if (w == 0) {
      if (k + 1 < 27) {
        gather((k + 1) & 1, lv_cur);
        if (k + 2 < 27) lv_cur = probe(k + 2);
      }
    } else {
      // B frags: wave's 32 couts, both k-halves (L1-hot: Wt[k] is 8KB)
      const u16* wk = Wt + (k << 12);
      short8 bf[2][2];
#pragma unroll
      for (int ct = 0; ct < 2; ct++)
#pragma unroll
        for (int h = 0; h < 2; h++)
          bf[ct][h] = *(const short8*)(wk + (((wj << 5) + (ct << 4) + col) << 6) + (h << 5) + (kg << 3));
      // A frags from LDS [chunk][row]: row = wi*32 + rt*16 + col, chunk kg+4h
      const char* slab = &ldsA[k & 1][0];
      short8 af[2][2];
#pragma unroll
      for (int rt = 0; rt < 2; rt++) {
        int row = (wi << 5) + (rt << 4) + col;
#pragma unroll
        for (int h = 0; h < 2; h++)
          af[rt][h] = *(const short8*)(slab + ((kg + (h << 2)) << 10) + (row << 4));
      }
#pragma unroll
      for (int rt = 0; rt < 2; rt++)
#pragma unroll
        for (int ct = 0; ct < 2; ct++) {
          acc[rt][ct] = __builtin_amdgcn_mfma_f32_16x16x32_bf16(af[rt][0], bf[ct][0], acc[rt][ct], 0, 0, 0);
          acc[rt][ct] = __builtin_amdgcn_mfma_f32_16x16x32_bf16(af[rt][1], bf[ct][1], acc[rt][ct], 0, 0, 0);
        }
    }
    __syncthreads();
  }

  // epilogue (consumers): BN + ReLU, zeros for invalid (r >= U) rows
  if (w > 0) {
#pragma unroll
    for (int ct = 0; ct < 2; ct++) {
      int c = (wj << 5) + (ct << 4) + col;
      float al = ab[c], be = ab[64 + c];
#pragma unroll
      for (int rt = 0; rt < 2; rt++) {
#pragma unroll
        for (int i = 0; i < 4; i++) {
          int r = rbase + (wi << 5) + (rt << 4) + (kg << 2) + i;
          if (r >= NPTS) continue;
          bool valid = ((u32)r < U);
          float vv = 0.f;
          if (valid) {
            vv = fmaf(acc[rt][ct][i], al, be);
            vv = vv > 0.f ? vv : 0.f;
          }
          out[((size_t)r << 6) + c] = vv;
        }
      }
    }
  }
}

extern "C" void kernel_launch(void* const* d_in, const int* in_sizes, int n_in,
                              void* d_out, int out_size, void* d_ws, size_t ws_size,
                              hipStream_t stream) {
  const int*   coords = (const int*)d_in[0];
  const float* feats  = (const float*)d_in[1];
  const float* W      = (const float*)d_in[2];
  const float* bns    = (const float*)d_in[3];
  const float* bnb    = (const float*)d_in[4];
  const float* bnm    = (const float*)d_in[5];
  const float* bnv    = (const float*)d_in[6];
  float* out = (float*)d_out;

  char* ws = (char*)d_ws;
  size_t off = 0;
  auto alloc = [&](size_t bytes) -> void* {
    void* p = ws + off;
    off += (bytes + 255) & ~(size_t)255;
    return p;
  };
  u32* lut      = (u32*)alloc((size_t)(NKEYS + 1) * 4);  // +1 zero sentinel
  u32* partials = (u32*)alloc((NPART + 8) * 4);
  int* keys     = (int*)alloc((size_t)NPTS * 4);
  int* r2k      = (int*)alloc((size_t)NPTS * 4);
  u16* fdsb     = (u16*)alloc((size_t)(NPTS + 1) * 64 * 2);  // +1 zero row
  u16* Wt       = (u16*)alloc((size_t)27 * 4096 * 2);
  float* ab     = (float*)alloc(128 * 4);
  (void)ws_size; (void)out_size; (void)n_in; (void)in_sizes;

  float* fds32 = out;   // d_out doubles as f32 staging for multi-point voxels

  hipMemsetAsync(lut, 0, (size_t)(NKEYS + 1) * 4, stream);
  hipMemsetAsync(fdsb + (size_t)NPTS * 64, 0, 128, stream);   // zero row

  k0a_bn<<<1, 64, 0, stream>>>(bns, bnb, bnm, bnv, ab);
  k0b_wt<<<(27 * 4096 + 255) / 256, 256, 0, stream>>>(W, Wt);
  k1_keys<<<(NPTS + 255) / 256, 256, 0, stream>>>(coords, keys, lut);
  k2a_part<<<NPART, 256, 0, stream>>>(lut, partials);
  k2b_top<<<1, NPART, 0, stream>>>(partials);
  k2c_fill<<<NPART, 256, 0, stream>>>(lut, partials, r2k, fds32);
  k3_seg<<<(NPTS * 16 + 255) / 256, 256, 0, stream>>>(feats, keys, lut, fds32, fdsb);
  k3b_fix<<<(NPTS * 4 + 255) / 256, 256, 0, stream>>>(r2k, lut, partials + NPART, fds32, fdsb);
  // 64 rows per block; 9376 blocks (multiple of 8 for the XCD swizzle)
  k4_conv<<<(NPTS + 63) / 64, 320, 0, stream>>>(lut, r2k, fdsb, Wt,
                                                partials + NPART, ab, out);
}

// Round 9
// 516.135 us; speedup vs baseline: 1.4333x; 1.4333x over previous
//
#include <hip/hip_runtime.h>
#include <hip/hip_bf16.h>

#define NPTS 600000
#define NKEYS (1 << 22)          // 2 * 128^3 compact key space
#define CHUNK 4096
#define NPART (NKEYS / CHUNK)    // 1024

typedef unsigned int u32;
typedef unsigned short u16;
typedef __attribute__((ext_vector_type(8))) short short8;   // 8 bf16 = 4 VGPRs
typedef __attribute__((ext_vector_type(4))) float f32x4;

__device__ __forceinline__ u16 f2bf(float x) {
  union { float f; u32 u; } c; c.f = x;
  u32 r = c.u + 0x7fffu + ((c.u >> 16) & 1u);   // RNE, inputs finite
  return (u16)(r >> 16);
}

// ---- K0a: fold BN into alpha/beta -------------------------------------------
__global__ void k0a_bn(const float* __restrict__ s, const float* __restrict__ b,
                       const float* __restrict__ m, const float* __restrict__ v,
                       float* __restrict__ ab) {
  int c = threadIdx.x;   // 64 threads
  float a = s[c] * rsqrtf(v[c] + 1e-5f);
  ab[c] = a;
  ab[64 + c] = b[c] - m[c] * a;
}

// ---- K0b: W[27][cin][cout] f32 -> Wt[27][cout][cin] bf16 --------------------
__global__ void k0b_wt(const float* __restrict__ W, u16* __restrict__ Wt) {
  int e = blockIdx.x * 256 + threadIdx.x;
  if (e >= 27 * 4096) return;
  int k = e >> 12, rem = e & 4095, cin = rem >> 6, cout = rem & 63;
  Wt[(k << 12) + (cout << 6) + cin] = f2bf(W[e]);
}

// ---- K1: compact keys + per-voxel point counts ------------------------------
__global__ void k1_keys(const int* __restrict__ coords, int* __restrict__ keys,
                        u32* __restrict__ lut) {
  int i = blockIdx.x * 256 + threadIdx.x;
  if (i >= NPTS) return;
  int4 c4 = *(const int4*)(coords + i * 4);
  int k = (c4.w << 21) | ((c4.x >> 1) << 14) | ((c4.y >> 1) << 7) | (c4.z >> 1);
  keys[i] = k;
  atomicAdd(&lut[k], 1u);   // count points per voxel (~600k atomics total)
}

// ---- K2a: per-chunk occupied-voxel counts -----------------------------------
__global__ void k2a_part(const u32* __restrict__ lut, u32* __restrict__ partials) {
  __shared__ u32 sd[256];
  int blk = blockIdx.x, t = threadIdx.x;
  const u32* p = lut + blk * CHUNK;
  u32 s = 0;
  for (int j = t; j < CHUNK; j += 256) s += (p[j] != 0u);
  sd[t] = s; __syncthreads();
  for (int o = 128; o > 0; o >>= 1) { if (t < o) sd[t] += sd[t + o]; __syncthreads(); }
  if (t == 0) partials[blk] = sd[0];
}

// ---- K2b: scan the 1024 partials (exclusive) + total U ----------------------
__global__ void k2b_top(u32* __restrict__ partials) {
  __shared__ u32 sh[NPART];
  int t = threadIdx.x;   // 1024 threads
  u32 x = partials[t];
  sh[t] = x; __syncthreads();
  for (int off = 1; off < NPART; off <<= 1) {
    u32 add = (t >= off) ? sh[t - off] : 0u;
    __syncthreads();
    sh[t] += add;
    __syncthreads();
  }
  partials[t] = sh[t] - x;                       // exclusive
  if (t == NPART - 1) partials[NPART] = sh[t];   // total unique count U
}

// ---- K2c: fill lut ((rank+1)|multi<<31 or 0), r2k, zero multi f32 rows ------
__global__ void k2c_fill(u32* __restrict__ lut, const u32* __restrict__ partials,
                         int* __restrict__ r2k, float* __restrict__ fds32) {
  __shared__ u32 tsum[256];
  int blk = blockIdx.x, t = threadIdx.x;
  int base = blk * CHUNK + t * 16;
  u32 loc[16]; u32 s = 0;
#pragma unroll
  for (int j = 0; j < 16; j++) { loc[j] = lut[base + j]; s += (loc[j] != 0u); }
  tsum[t] = s; __syncthreads();
  for (int off = 1; off < 256; off <<= 1) {
    u32 add = (t >= off) ? tsum[t - off] : 0u;
    __syncthreads();
    tsum[t] += add;
    __syncthreads();
  }
  u32 rank = partials[blk] + tsum[t] - s;   // exclusive rank for first elem
#pragma unroll
  for (int j = 0; j < 16; j++) {
    if (loc[j]) {
      u32 flag = (loc[j] > 1u) ? 0x80000000u : 0u;
      lut[base + j] = (rank + 1u) | flag;
      r2k[rank] = base + j;
      if (flag) {   // zero the f32 accumulation row for multi-point voxels
        float4 z = {0.f, 0.f, 0.f, 0.f};
        float* d = fds32 + ((size_t)rank << 6);
#pragma unroll
        for (int c = 0; c < 16; c++) *(float4*)(d + c * 4) = z;
      }
      rank++;
    } else lut[base + j] = 0u;
  }
}

// ---- K3: fused segment-sum: singles -> bf16 direct, multis -> f32 atomics ---
__global__ void k3_seg(const float* __restrict__ feats, const int* __restrict__ keys,
                       const u32* __restrict__ lut, float* __restrict__ fds32,
                       u16* __restrict__ fdsb) {
  int idx = blockIdx.x * 256 + threadIdx.x;   // NPTS*16 threads, 4 ch each
  if (idx >= NPTS * 16) return;
  int i = idx >> 4, q = (idx & 15) << 2;
  u32 lv = lut[keys[i]];
  u32 r = (lv & 0x7fffffffu) - 1u;
  float4 v = *(const float4*)(feats + (size_t)i * 64 + q);
  if (lv >> 31) {               // ~13% of points: shared voxel, accumulate f32
    float* dst = fds32 + ((size_t)r << 6) + q;
    atomicAdd(dst + 0, v.x); atomicAdd(dst + 1, v.y);
    atomicAdd(dst + 2, v.z); atomicAdd(dst + 3, v.w);
  } else {                      // ~87%: sole occupant, convert + plain store
    ushort4 o;
    o.x = f2bf(v.x); o.y = f2bf(v.y); o.z = f2bf(v.z); o.w = f2bf(v.w);
    *(ushort4*)(fdsb + ((size_t)r << 6) + q) = o;
  }
}

// ---- K3b: convert only multi-voxel rows f32 -> bf16 -------------------------
__global__ void k3b_fix(const int* __restrict__ r2k, const u32* __restrict__ lut,
                        const u32* __restrict__ pU,
                        const float* __restrict__ fds32, u16* __restrict__ fdsb) {
  int idx = blockIdx.x * 256 + threadIdx.x;   // NPTS*4 threads, 16 ch each
  int r = idx >> 2;
  if (r >= (int)(*pU)) return;
  u32 lv = lut[r2k[r]];
  if (!(lv >> 31)) return;
  int q = (idx & 3) << 4;
  const float* src = fds32 + ((size_t)r << 6) + q;
  u16* dst = fdsb + ((size_t)r << 6) + q;
#pragma unroll
  for (int j = 0; j < 4; j++) {
    float4 v = *(const float4*)(src + j * 4);
    ushort4 o;
    o.x = f2bf(v.x); o.y = f2bf(v.y); o.z = f2bf(v.z); o.w = f2bf(v.w);
    *(ushort4*)(dst + j * 4) = o;
  }
}

// ---- K4: producer/consumer gather-GEMM + BN/ReLU (exec-masked gathers) ------
// Block = 320 thr (5 waves), 64 output rows. Wave 0 = producer: per offset k,
// lane l probes lut (issued 2 iters ahead) then gathers the 128B fdsb row for
// its output row -- but ONLY for hit lanes (~13%): the `if (lv)` exec mask
// suppresses memory requests for miss lanes, cutting scattered TA work ~7.5x
// vs the R7/R8 branchless-sentinel design. Loads batch into 8 temps (zeros
// for misses), then 8 unconditional ds_writes (bank-rotated by row&7).
// Waves 1-4 = consumers: 16-cout block each, read A from the LDS ring +
// 2 coalesced L1-hot B loads, 8 MFMAs per offset. One barrier per offset;
// ring slot k&1 read while (k+1)&1 is written (disjoint).
__global__ __launch_bounds__(320) void k4_conv(
    const u32* __restrict__ lut, const int* __restrict__ r2k,
    const u16* __restrict__ fdsb, const u16* __restrict__ Wt,
    const u32* __restrict__ pU, const float* __restrict__ ab,
    float* __restrict__ out) {
  __shared__ __align__(16) char ldsA[2][8192];   // ring: 64 rows x 128B
  const u32 U = *pU;
  int tid = threadIdx.x;
  int w = tid >> 6, l = tid & 63;
  // XCD-bijective swizzle (grid multiple of 8): rank-contiguous chunks per XCD.
  int bid = blockIdx.x;
  int cpx = (int)gridDim.x >> 3;
  int swz = (bid & 7) * cpx + (bid >> 3);
  int rbase = swz * 64;

  // ---- producer state (wave 0): lane l owns output row rbase + l ----
  int key = -1, x = 0, y = 0, z = 0;
  if (w == 0) {
    int r = rbase + l;
    key = ((u32)r < U) ? r2k[r] : -1;
    z = key & 127; y = (key >> 7) & 127; x = (key >> 14) & 127;
  }
  // branchless lut probe for offset k (sentinel entry NKEYS == 0 for OOB)
  auto probe = [&](int k) -> u32 {
    int dx = k / 9 - 1, dy = (k / 3) % 3 - 1, dz = k % 3 - 1;
    int nx = x + dx, ny = y + dy, nz = z + dz;
    bool ok = (key >= 0) & ((u32)nx < 128u) & ((u32)ny < 128u) & ((u32)nz < 128u);
    int a = ok ? (key + dx * 16384 + dy * 128 + dz) : NKEYS;
    return lut[a];
  };
  // exec-masked gather: load the 128B row only on hit lanes, zeros otherwise
  const short8 z8 = {0, 0, 0, 0, 0, 0, 0, 0};
  auto gather = [&](int slot, u32 lvv) {
    short8 t0 = z8, t1 = z8, t2 = z8, t3 = z8,
           t4 = z8, t5 = z8, t6 = z8, t7 = z8;
    if (lvv) {   // per-lane exec mask: miss lanes issue NO memory requests
      const u16* fr = fdsb + ((size_t)((lvv & 0x7fffffffu) - 1u) << 6);
      t0 = *(const short8*)(fr);      t1 = *(const short8*)(fr + 8);
      t2 = *(const short8*)(fr + 16); t3 = *(const short8*)(fr + 24);
      t4 = *(const short8*)(fr + 32); t5 = *(const short8*)(fr + 40);
      t6 = *(const short8*)(fr + 48); t7 = *(const short8*)(fr + 56);
    }
    char* dst = &ldsA[slot][l * 128];
    int r7 = l & 7;
    *(short8*)(dst + (((0 + r7) & 7) << 4)) = t0;
    *(short8*)(dst + (((1 + r7) & 7) << 4)) = t1;
    *(short8*)(dst + (((2 + r7) & 7) << 4)) = t2;
    *(short8*)(dst + (((3 + r7) & 7) << 4)) = t3;
    *(short8*)(dst + (((4 + r7) & 7) << 4)) = t4;
    *(short8*)(dst + (((5 + r7) & 7) << 4)) = t5;
    *(short8*)(dst + (((6 + r7) & 7) << 4)) = t6;
    *(short8*)(dst + (((7 + r7) & 7) << 4)) = t7;
  };

  // ---- consumer state (waves 1-4): one 16-cout block each ----
  int ct = w - 1;
  int col = l & 15, kg = l >> 4;
  f32x4 acc[4] = {};   // 4 row-tiles of 16

  // prologue: fill slot 0, prime the probe pipeline
  u32 lv_cur = 0;
  if (w == 0) {
    gather(0, probe(0));
    lv_cur = probe(1);
  }
  __syncthreads();

  for (int k = 0; k < 27; k++) {
    if (w == 0) {
      if (k + 1 < 27) {
        gather((k + 1) & 1, lv_cur);          // uses probe issued last iter
        if (k + 2 < 27) lv_cur = probe(k + 2);
      }
    } else {
      const u16* wk = Wt + (k << 12) + (((ct << 4) + col) << 6) + (kg << 3);
      short8 b0 = *(const short8*)(wk);
      short8 b1 = *(const short8*)(wk + 32);
      const char* slab = &ldsA[k & 1][0];
#pragma unroll
      for (int rt = 0; rt < 4; rt++) {
        int row = (rt << 4) + col;
        const char* rp = slab + row * 128;
        int r7 = row & 7;
        short8 a0 = *(const short8*)(rp + (((kg + r7) & 7) << 4));
        short8 a1 = *(const short8*)(rp + (((kg + 4 + r7) & 7) << 4));
        acc[rt] = __builtin_amdgcn_mfma_f32_16x16x32_bf16(a0, b0, acc[rt], 0, 0, 0);
        acc[rt] = __builtin_amdgcn_mfma_f32_16x16x32_bf16(a1, b1, acc[rt], 0, 0, 0);
      }
    }
    __syncthreads();
  }

  // epilogue (consumers): BN + ReLU, zeros for invalid (r >= U) rows
  if (w > 0) {
    int c = (ct << 4) | col;
    float al = ab[c], be = ab[64 + c];
#pragma unroll
    for (int rt = 0; rt < 4; rt++) {
#pragma unroll
      for (int i = 0; i < 4; i++) {
        int r = rbase + (rt << 4) + (kg << 2) + i;
        if (r >= NPTS) continue;
        bool valid = ((u32)r < U);
        float vv = 0.f;
        if (valid) {
          vv = fmaf(acc[rt][i], al, be);
          vv = vv > 0.f ? vv : 0.f;
        }
        out[((size_t)r << 6) + c] = vv;
      }
    }
  }
}

extern "C" void kernel_launch(void* const* d_in, const int* in_sizes, int n_in,
                              void* d_out, int out_size, void* d_ws, size_t ws_size,
                              hipStream_t stream) {
  const int*   coords = (const int*)d_in[0];
  const float* feats  = (const float*)d_in[1];
  const float* W      = (const float*)d_in[2];
  const float* bns    = (const float*)d_in[3];
  const float* bnb    = (const float*)d_in[4];
  const float* bnm    = (const float*)d_in[5];
  const float* bnv    = (const float*)d_in[6];
  float* out = (float*)d_out;

  char* ws = (char*)d_ws;
  size_t off = 0;
  auto alloc = [&](size_t bytes) -> void* {
    void* p = ws + off;
    off += (bytes + 255) & ~(size_t)255;
    return p;
  };
  u32* lut      = (u32*)alloc((size_t)(NKEYS + 1) * 4);  // +1 zero sentinel
  u32* partials = (u32*)alloc((NPART + 8) * 4);
  int* keys     = (int*)alloc((size_t)NPTS * 4);
  int* r2k      = (int*)alloc((size_t)NPTS * 4);
  u16* fdsb     = (u16*)alloc((size_t)(NPTS + 1) * 64 * 2);
  u16* Wt       = (u16*)alloc((size_t)27 * 4096 * 2);
  float* ab     = (float*)alloc(128 * 4);
  (void)ws_size; (void)out_size; (void)n_in; (void)in_sizes;

  float* fds32 = out;   // d_out doubles as f32 staging for multi-point voxels

  hipMemsetAsync(lut, 0, (size_t)(NKEYS + 1) * 4, stream);

  k0a_bn<<<1, 64, 0, stream>>>(bns, bnb, bnm, bnv, ab);
  k0b_wt<<<(27 * 4096 + 255) / 256, 256, 0, stream>>>(W, Wt);
  k1_keys<<<(NPTS + 255) / 256, 256, 0, stream>>>(coords, keys, lut);
  k2a_part<<<NPART, 256, 0, stream>>>(lut, partials);
  k2b_top<<<1, NPART, 0, stream>>>(partials);
  k2c_fill<<<NPART, 256, 0, stream>>>(lut, partials, r2k, fds32);
  k3_seg<<<(NPTS * 16 + 255) / 256, 256, 0, stream>>>(feats, keys, lut, fds32, fdsb);
  k3b_fix<<<(NPTS * 4 + 255) / 256, 256, 0, stream>>>(r2k, lut, partials + NPART, fds32, fdsb);
  // 64 rows per block; 9376 blocks (multiple of 8 for the XCD swizzle)
  k4_conv<<<(NPTS + 63) / 64, 320, 0, stream>>>(lut, r2k, fdsb, Wt,
                                                partials + NPART, ab, out);
}